// Round 10
// baseline (153.992 us; speedup 1.0000x reference)
//
#include <hip/hip_runtime.h>
#include <math.h>

#define N_TOK 16384
#define HDIM  2048
#define NEXP  64
#define TOPK  8
#define NKS   4             // K split factor
#define KSEG  (HDIM / NKS)  // 512 k per block
#define KCH   32            // k per LDS chunk
#define NCH   (KSEG / KCH)  // 16

// d_ws layout:
//   [0, 32 MiB)   : part  — partial logits f64 [NKS][N_TOK][64]
//   [33 MiB, ...) : stats — f32 probsum[64], counts[64], then int flag
#define PART_OFF  0
#define STATS_OFF (33u << 20)

typedef double d4 __attribute__((ext_vector_type(4)));

// 16-hypothesis MFMA layout probe (1 wave), exact integer arithmetic.
// flag = 1 + ai*8 + bi*4 + sf*2 + tr, or 0 if none match. (R9: matched.)
__global__ void mfma_probe_kernel(int* __restrict__ flag) {
    const int l = threadIdx.x;
    const int i16 = l & 15, q = l >> 4;
    const int r4 = l >> 2,  m4 = l & 3;
    int fv = 0;
#pragma unroll
    for (int ai = 0; ai < 2; ++ai)
#pragma unroll
    for (int bi = 0; bi < 2; ++bi) {
        const int ra = ai ? r4 : i16, ka = ai ? m4 : q;
        const int cb = bi ? r4 : i16, kb = bi ? m4 : q;
        double a = (double)(ra * 4 + ka + 1);            // A[ra][ka]
        double b = (double)((kb + 1) * 100 + 3 * cb);    // B[kb][cb]
        d4 acc = {0., 0., 0., 0.};
        acc = __builtin_amdgcn_mfma_f64_16x16x4f64(a, b, acc, 0, 0, 0);
#pragma unroll
        for (int sf = 0; sf < 2; ++sf)
#pragma unroll
        for (int tr = 0; tr < 2; ++tr) {
            int ok = 1;
#pragma unroll
            for (int r = 0; r < 4; ++r) {
                const int p   = sf ? (q + 4 * r) : (4 * q + r);
                const int row = tr ? i16 : p;
                const int col = tr ? p : i16;
                double ref = 0.0;
#pragma unroll
                for (int k = 0; k < 4; ++k)
                    ref += (double)(row * 4 + k + 1) * (double)((k + 1) * 100 + 3 * col);
                ok &= (acc[r] == ref);
            }
            if (__all(ok) && fv == 0) fv = 1 + ai * 8 + bi * 4 + sf * 2 + tr;
        }
    }
    if (l == 0) *flag = fv;
}

// MFMA f64 GEMM with k-permuted LDS (col p holds k(p) = 4*(p&7) + (p>>3)),
// so a lane's per-kq fragment walk is contiguous -> ds_read_b128 feeds TWO
// MFMA k-steps. Staging pre-swizzles the global source (thread (row,cu)
// writes cols 8cu..8cu+7 = k {8j+cu, 8j+cu+4}); W staged straight from raw
// f32 W[e][k] (no transpose kernel). All addressing verified 8-words/bank
// minimum (conflict-free) for every flag variant.
__global__ __launch_bounds__(256) void gemm_mfma_kernel(const float* __restrict__ X,
                                                        const float* __restrict__ W,
                                                        const int* __restrict__ flag,
                                                        double* __restrict__ part) {
    const int f = *flag;
    if (f == 0) return;                              // layout unresolved -> VALU path
    const int fb = f - 1;
    const int ai = (fb >> 3) & 1, bi = (fb >> 2) & 1;
    const int sf = (fb >> 1) & 1, tr = fb & 1;

    const int tt  = blockIdx.x >> 2;
    const int ks  = blockIdx.x & 3;
    const int tid = threadIdx.x;
    const int l   = tid & 63;
    const int wv  = tid >> 6;
    const int wr  = wv >> 1, wc = wv & 1;
    const int tok0 = tt * 64;
    const int k0   = ks * KSEG;

    const int i16 = l & 15, q = l >> 4, r4 = l >> 2, m4 = l & 3;
    const int ra = ai ? r4 : i16, ka = ai ? m4 : q;  // A element this lane feeds
    const int cb = bi ? r4 : i16, kb = bi ? m4 : q;  // B element this lane feeds

    __shared__ double Xs[64][34];                    // 64 tok x 32 k' (+2 pad)
    __shared__ double Ws[64][34];                    // 64 exp x 32 k' (+2 pad)

    d4 acc[2][2];
#pragma unroll
    for (int i = 0; i < 2; ++i)
#pragma unroll
        for (int j = 0; j < 2; ++j) acc[i][j] = (d4){0., 0., 0., 0.};

    // staging: thread -> row rs = tid>>2 (0..63), cu = tid&3.
    // double2 j at cols (8cu+2j, 8cu+2j+1) holds k = 8j+cu and 8j+cu+4.
    const int rs = tid >> 2, cu = tid & 3;
    const float* xg = X + (size_t)(tok0 + rs) * HDIM + k0 + cu;
    const float* wg = W + (size_t)rs * HDIM + k0 + cu;

    float fx[8], fw[8];
#pragma unroll
    for (int j = 0; j < 4; ++j) {
        fx[2 * j]     = xg[8 * j];
        fx[2 * j + 1] = xg[8 * j + 4];
        fw[2 * j]     = wg[8 * j];
        fw[2 * j + 1] = wg[8 * j + 4];
    }

    for (int c = 0; c < NCH; ++c) {
        __syncthreads();                             // readers of previous chunk done
#pragma unroll
        for (int j = 0; j < 4; ++j) {
            double2 dx; dx.x = (double)fx[2 * j]; dx.y = (double)fx[2 * j + 1];
            double2 dw; dw.x = (double)fw[2 * j]; dw.y = (double)fw[2 * j + 1];
            *(double2*)&Xs[rs][8 * cu + 2 * j] = dx;
            *(double2*)&Ws[rs][8 * cu + 2 * j] = dw;
        }
        __syncthreads();
        if (c + 1 < NCH) {                           // prefetch next chunk into regs
            const float* xn = xg + (c + 1) * KCH;
            const float* wn = wg + (c + 1) * KCH;
#pragma unroll
            for (int j = 0; j < 4; ++j) {
                fx[2 * j]     = xn[8 * j];
                fx[2 * j + 1] = xn[8 * j + 4];
                fw[2 * j]     = wn[8 * j];
                fw[2 * j + 1] = wn[8 * j + 4];
            }
        }
        const double* pa0 = &Xs[wr * 32 + ra][8 * ka];
        const double* pa1 = &Xs[wr * 32 + 16 + ra][8 * ka];
        const double* pb0 = &Ws[wc * 32 + cb][8 * kb];
        const double* pb1 = &Ws[wc * 32 + 16 + cb][8 * kb];
#pragma unroll
        for (int t = 0; t < 4; ++t) {                // each t: 2 k-steps, 8 MFMAs
            double2 a0 = *(const double2*)(pa0 + 2 * t);
            double2 a1 = *(const double2*)(pa1 + 2 * t);
            double2 b0 = *(const double2*)(pb0 + 2 * t);
            double2 b1 = *(const double2*)(pb1 + 2 * t);
            acc[0][0] = __builtin_amdgcn_mfma_f64_16x16x4f64(a0.x, b0.x, acc[0][0], 0, 0, 0);
            acc[0][1] = __builtin_amdgcn_mfma_f64_16x16x4f64(a0.x, b1.x, acc[0][1], 0, 0, 0);
            acc[1][0] = __builtin_amdgcn_mfma_f64_16x16x4f64(a1.x, b0.x, acc[1][0], 0, 0, 0);
            acc[1][1] = __builtin_amdgcn_mfma_f64_16x16x4f64(a1.x, b1.x, acc[1][1], 0, 0, 0);
            acc[0][0] = __builtin_amdgcn_mfma_f64_16x16x4f64(a0.y, b0.y, acc[0][0], 0, 0, 0);
            acc[0][1] = __builtin_amdgcn_mfma_f64_16x16x4f64(a0.y, b1.y, acc[0][1], 0, 0, 0);
            acc[1][0] = __builtin_amdgcn_mfma_f64_16x16x4f64(a1.y, b0.y, acc[1][0], 0, 0, 0);
            acc[1][1] = __builtin_amdgcn_mfma_f64_16x16x4f64(a1.y, b1.y, acc[1][1], 0, 0, 0);
        }
    }

    double* pbase = part + (size_t)ks * N_TOK * NEXP;
#pragma unroll
    for (int rt = 0; rt < 2; ++rt)
#pragma unroll
        for (int ct = 0; ct < 2; ++ct)
#pragma unroll
            for (int r = 0; r < 4; ++r) {
                const int p    = sf ? (q + 4 * r) : (4 * q + r);
                const int dtok = tr ? i16 : p;
                const int dex  = tr ? p : i16;
                const int tok  = tok0 + wr * 32 + rt * 16 + dtok;
                const int ex   = wc * 32 + ct * 16 + dex;
                pbase[(size_t)tok * NEXP + ex] = acc[rt][ct][r];
            }
}

// VALU fallback (R7 structure, proven math). Runs only if flag == 0.
// W staged from raw f32 W[e][k] (transpose during staging).
__global__ __launch_bounds__(512, 4) void gemm_valu_kernel(const float* __restrict__ X,
                                                           const float* __restrict__ W,
                                                           const int* __restrict__ flag,
                                                           double* __restrict__ part) {
    if (*flag != 0) return;                          // MFMA path verified -> skip
    const int tt   = blockIdx.x >> 2;
    const int ks   = blockIdx.x & 3;
    const int tid  = threadIdx.x;
    const int lane = tid & 63;                       // expert
    const int wv   = tid >> 6;                       // 0..7
    const int tok0 = tt * 64;
    const int k0   = ks * KSEG;

    __shared__ double xs[64][18];
    __shared__ double wsh[16][66];

    double acc[8];
#pragma unroll
    for (int t = 0; t < 8; ++t) acc[t] = 0.0;

    const int sx_tok = tid >> 3;
    const int sx_k   = (tid & 7) * 2;
    const float* xg  = X + (size_t)(tok0 + sx_tok) * HDIM + k0 + sx_k;
    const int sw_k = tid >> 5;                       // 0..15
    const int sw_e = (tid & 31) * 2;                 // 0..62
    const float* wg0 = W + (size_t)sw_e * HDIM + k0 + sw_k;
    const float* wg1 = W + (size_t)(sw_e + 1) * HDIM + k0 + sw_k;

    float2 px = *(const float2*)xg;
    float  pa = *wg0, pb2 = *wg1;

    for (int c = 0; c < KSEG / 16; ++c) {
        __syncthreads();
        {
            double2 xv; xv.x = (double)px.x; xv.y = (double)px.y;
            *(double2*)&xs[sx_tok][sx_k] = xv;
            double2 wv2; wv2.x = (double)pa; wv2.y = (double)pb2;
            *(double2*)&wsh[sw_k][sw_e] = wv2;
        }
        __syncthreads();
        if (c + 1 < KSEG / 16) {
            px  = *(const float2*)(xg + (c + 1) * 16);
            pa  = wg0[(c + 1) * 16];
            pb2 = wg1[(c + 1) * 16];
        }
        double wr_[16];
#pragma unroll
        for (int j = 0; j < 16; ++j) wr_[j] = wsh[j][lane];
#pragma unroll
        for (int t = 0; t < 8; ++t) {
            const int trr = wv * 8 + t;
#pragma unroll
            for (int kp = 0; kp < 8; ++kp) {
                double2 xv = *(const double2*)&xs[trr][kp * 2];
                acc[t] = fma(xv.x, wr_[kp * 2],     acc[t]);
                acc[t] = fma(xv.y, wr_[kp * 2 + 1], acc[t]);
            }
        }
    }

    double* pb = part + ((size_t)ks * N_TOK + tok0 + wv * 8) * NEXP + lane;
#pragma unroll
    for (int t = 0; t < 8; ++t)
        pb[(size_t)t * NEXP] = acc[t];
}

// Top-k (proven): coalesced stage -> f32-score argmax ladder, ties -> min idx.
__global__ __launch_bounds__(256) void topk_kernel(const double* __restrict__ part,
                                                   float* __restrict__ outIdx,
                                                   float* __restrict__ outW,
                                                   float* __restrict__ stats) {
    __shared__ float sc_s[32][65];
    __shared__ float lds_counts[NEXP];
    __shared__ float psum_part[4][NEXP];
    const int tid  = threadIdx.x;
    const int lane = tid & 63;
    const int w    = tid >> 6;
    if (tid < NEXP) lds_counts[tid] = 0.f;

    const int t0 = blockIdx.x * 32;
#pragma unroll
    for (int p = 0; p < 8; ++p) {
        const int idx = p * 256 + tid;
        const int t   = idx >> 6;
        const int e   = idx & 63;
        const double* pp = part + ((size_t)(t0 + t)) * NEXP + e;
        double l = (pp[0] + pp[(size_t)N_TOK * NEXP]) +
                   (pp[2 * (size_t)N_TOK * NEXP] + pp[3 * (size_t)N_TOK * NEXP]);
        sc_s[t][e] = (float)(1.0 / (1.0 + exp(-l)));
    }
    __syncthreads();

    float ps = 0.f;
    for (int i = 0; i < 8; ++i) {
        const int tloc = w * 8 + i;
        const int t    = t0 + tloc;
        float s = sc_s[tloc][lane];

        float rs = s;
#pragma unroll
        for (int off = 32; off; off >>= 1) rs += __shfl_xor(rs, off);
        ps += s / (rs + 1e-9f);

        float cur = s;
        float denom = 0.f;
        int   wi = 0;
        float wvv = 0.f;
#pragma unroll
        for (int k = 0; k < TOPK; ++k) {
            float m = cur; int mi = lane;
#pragma unroll
            for (int off = 32; off; off >>= 1) {
                float om = __shfl_xor(m, off);
                int   oi = __shfl_xor(mi, off);
                if (om > m || (om == m && oi < mi)) { m = om; mi = oi; }
            }
            denom += m;
            if (lane == k)  { wi = mi; wvv = m; }
            if (lane == mi) cur = -1e30f;
        }
        if (lane < TOPK) {
            outIdx[(size_t)t * TOPK + lane] = (float)wi;
            outW  [(size_t)t * TOPK + lane] = wvv / (denom + 1e-9f);
            atomicAdd(&lds_counts[wi], 1.f);
        }
    }
    psum_part[w][lane] = ps;
    __syncthreads();
    if (tid < NEXP) {
        float tot = psum_part[0][tid] + psum_part[1][tid] +
                    psum_part[2][tid] + psum_part[3][tid];
        atomicAdd(&stats[tid], tot);
        atomicAdd(&stats[NEXP + tid], lds_counts[tid]);
    }
}

__global__ void aux_kernel(const float* __restrict__ stats, float* __restrict__ out) {
    const int e = threadIdx.x;
    float prob = stats[e] / (float)N_TOK;
    float cnt  = stats[NEXP + e];
    float loadf = cnt / ((float)N_TOK * TOPK);
    float S = prob;
#pragma unroll
    for (int off = 32; off; off >>= 1) S += __shfl_xor(S, off);
    float pn = prob / (S + 1e-9f);
    float v  = loadf * pn;
#pragma unroll
    for (int off = 32; off; off >>= 1) v += __shfl_xor(v, off);
    if (e == 0) out[2 * N_TOK * TOPK] = 0.001f * v * (float)NEXP;
}

extern "C" void kernel_launch(void* const* d_in, const int* in_sizes, int n_in,
                              void* d_out, int out_size, void* d_ws, size_t ws_size,
                              hipStream_t stream) {
    (void)in_sizes; (void)n_in; (void)out_size; (void)ws_size;
    const float* X = (const float*)d_in[0];
    const float* W = (const float*)d_in[1];
    float* out = (float*)d_out;
    char*  ws  = (char*)d_ws;
    double* part  = (double*)(ws + PART_OFF);
    float*  stats = (float*)(ws + STATS_OFF);
    int*    flag  = (int*)(stats + 128);

    hipMemsetAsync(stats, 0, 132 * sizeof(float), stream);
    mfma_probe_kernel<<<1, 64, 0, stream>>>(flag);
    gemm_mfma_kernel<<<1024, 256, 0, stream>>>(X, W, flag, part);
    gemm_valu_kernel<<<1024, 512, 0, stream>>>(X, W, flag, part);
    topk_kernel<<<512, 256, 0, stream>>>(part, out, out + N_TOK * TOPK, stats);
    aux_kernel<<<1, 64, 0, stream>>>(stats, out);
}